// Round 4
// baseline (367.570 us; speedup 1.0000x reference)
//
#include <hip/hip_runtime.h>

// Problem constants: B=8, C=512, L=4096, Ci=256, K=L/2=2048
#define BATCH 8
#define CIN   512
#define LEN   4096
#define CI    256
#define KLEN  2048

typedef _Float16 half_t;
typedef _Float16 half2_t __attribute__((ext_vector_type(2)));
typedef _Float16 half4_t __attribute__((ext_vector_type(4)));
typedef _Float16 half8_t __attribute__((ext_vector_type(8)));
typedef float    floatx4 __attribute__((ext_vector_type(4)));

// async global->LDS 16B: LDS side is wave-uniform base + lane*16;
// GLOBAL side is a per-lane gather (arbitrary per-lane address).
__device__ __forceinline__ void async16(void* lds_dst, const void* g_src) {
    __builtin_amdgcn_global_load_lds(
        (const __attribute__((address_space(1))) unsigned int*)g_src,
        (__attribute__((address_space(3))) unsigned int*)lds_dst,
        16, 0, 0);
}

// ---------------------------------------------------------------------------
// Kernel A: convert+transpose x[b][c][l] f32 -> xhT[b][l][c] f16.
// ---------------------------------------------------------------------------
__global__ __launch_bounds__(256) void xpose_kernel(
    const float* __restrict__ x, half_t* __restrict__ xhT)
{
    __shared__ half_t tile[64][72];
    const int b = blockIdx.z, c0 = blockIdx.y * 64, l0 = blockIdx.x * 64;
    const int t = threadIdx.x;
    #pragma unroll
    for (int i = 0; i < 4; i++) {
        int fid = t + 256 * i;
        int c = fid >> 4, lb = (fid & 15) << 2;
        float4 v = *(const float4*)(x + ((size_t)b * CIN + c0 + c) * LEN + l0 + lb);
        tile[lb + 0][c] = (half_t)v.x;
        tile[lb + 1][c] = (half_t)v.y;
        tile[lb + 2][c] = (half_t)v.z;
        tile[lb + 3][c] = (half_t)v.w;
    }
    __syncthreads();
    #pragma unroll
    for (int i = 0; i < 2; i++) {
        int fid = t + 256 * i;
        int l = fid >> 3, cb = (fid & 7) << 3;
        half8_t v = *(const half8_t*)&tile[l][cb];
        *(half8_t*)(xhT + ((size_t)b * LEN + l0 + l) * CIN + c0 + cb) = v;
    }
}

// ---------------------------------------------------------------------------
// Kernel B: convert weights to fp16. Wh[768][512], wzh[512][256].
// ---------------------------------------------------------------------------
__global__ __launch_bounds__(256) void wconv_kernel(
    const float* __restrict__ tw, const float* __restrict__ pw,
    const float* __restrict__ gw, const float* __restrict__ wzw,
    half_t* __restrict__ Wh, half_t* __restrict__ wzh)
{
    size_t base = ((size_t)blockIdx.x * 256 + threadIdx.x) * 8;
    const float* src;
    half_t* dst;
    if (base < 768 * 512) {
        size_t o = base >> 9, c = base & 511;
        src = (o < 256 ? tw + o * 512
                       : (o < 512 ? pw + (o - 256) * 512 : gw + (o - 512) * 512)) + c;
        dst = Wh + base;
    } else {
        size_t off = base - 768 * 512;
        src = wzw + off;
        dst = wzh + off;
    }
    float4 a = *(const float4*)src, b2 = *(const float4*)(src + 4);
    half8_t h = { (half_t)a.x, (half_t)a.y, (half_t)a.z, (half_t)a.w,
                  (half_t)b2.x, (half_t)b2.y, (half_t)b2.z, (half_t)b2.w };
    *(half8_t*)dst = h;
}

// ---------------------------------------------------------------------------
// Kernel 1: MFMA projection GEMM, fragment-order LDS staging (conflict-free).
// out[o,l] = sum_c Wh[o,c] xhT[l,c]; o=0..767 = theta/phi/g; maxpool fused.
// g written to gperm with k-permutation sigma so attn's PV can run K=32.
// Grid (L/128, 6, B), 128x128 tile, BK=32.
// LDS layout: granule (rb,quad,ln): row rb*16+ln, halves quad*8.. -> read at
// base + lane*16 (contiguous wave b128, zero conflicts).
// ---------------------------------------------------------------------------
__global__ __launch_bounds__(256, 2) void projmm_kernel(
    const half_t* __restrict__ xhT, const half_t* __restrict__ Wh,
    const float* __restrict__ tb, const float* __restrict__ pb,
    const float* __restrict__ gb,
    half_t* __restrict__ thetaT, half_t* __restrict__ phiT,
    half_t* __restrict__ gperm)
{
    __shared__ half_t wsm[128 * 32];
    __shared__ half_t xsm[128 * 32];

    const int b  = blockIdx.z;
    const int o0 = blockIdx.y * 128;
    const int l0 = blockIdx.x * 128;
    const int t  = threadIdx.x;
    const int lane = t & 63, w = t >> 6;
    const int ln = lane & 15, quad = lane >> 4;
    const int wm = w >> 1, wn = w & 1;

    floatx4 acc[4][4];
    #pragma unroll
    for (int mi = 0; mi < 4; mi++)
        #pragma unroll
        for (int nj = 0; nj < 4; nj++) acc[mi][nj] = (floatx4)(0.0f);

    const half_t* Wb = Wh + (size_t)o0 * 512;
    const half_t* xb = xhT + ((size_t)b * LEN + l0) * CIN;

    for (int k0 = 0; k0 < 512; k0 += 32) {
        __syncthreads();
        #pragma unroll
        for (int it = 0; it < 2; it++) {
            int grp = w * 2 + it;           // rb = grp (0..7)
            async16(&wsm[grp * 512],
                    Wb + (size_t)(grp * 16 + ln) * 512 + k0 + quad * 8);
            async16(&xsm[grp * 512],
                    xb + (size_t)(grp * 16 + ln) * CIN + k0 + quad * 8);
        }
        __syncthreads();
        half8_t af[4], bf[4];
        #pragma unroll
        for (int mi = 0; mi < 4; mi++)
            af[mi] = *(const half8_t*)&wsm[(wm * 4 + mi) * 512 + lane * 8];
        #pragma unroll
        for (int nj = 0; nj < 4; nj++)
            bf[nj] = *(const half8_t*)&xsm[(wn * 4 + nj) * 512 + lane * 8];
        #pragma unroll
        for (int mi = 0; mi < 4; mi++)
            #pragma unroll
            for (int nj = 0; nj < 4; nj++)
                acc[mi][nj] = __builtin_amdgcn_mfma_f32_16x16x32_f16(
                                  af[mi], bf[nj], acc[mi][nj], 0, 0, 0);
    }

    const int which = o0 >> 8;          // 0=theta, 1=phi, 2=g
    const int obase = o0 & 255;
    const float* Bp = which == 0 ? tb : (which == 1 ? pb : gb);

    float bias[4][4];
    #pragma unroll
    for (int mi = 0; mi < 4; mi++)
        #pragma unroll
        for (int r = 0; r < 4; r++)
            bias[mi][r] = Bp[obase + wm * 64 + mi * 16 + quad * 4 + r];

    if (which == 0) {
        #pragma unroll
        for (int mi = 0; mi < 4; mi++) {
            int o = obase + wm * 64 + mi * 16 + quad * 4;
            #pragma unroll
            for (int nj = 0; nj < 4; nj++) {
                int l = l0 + wn * 64 + nj * 16 + ln;
                half4_t v = { (half_t)(acc[mi][nj][0] + bias[mi][0]),
                              (half_t)(acc[mi][nj][1] + bias[mi][1]),
                              (half_t)(acc[mi][nj][2] + bias[mi][2]),
                              (half_t)(acc[mi][nj][3] + bias[mi][3]) };
                *(half4_t*)(thetaT + ((size_t)b * LEN + l) * CI + o) = v;
            }
        }
    } else {
        #pragma unroll
        for (int mi = 0; mi < 4; mi++) {
            int o = obase + wm * 64 + mi * 16 + quad * 4;
            #pragma unroll
            for (int nj = 0; nj < 4; nj++) {
                int l = l0 + wn * 64 + nj * 16 + ln;
                float mx[4];
                #pragma unroll
                for (int r = 0; r < 4; r++) {
                    float other = __shfl_xor(acc[mi][nj][r], 1);
                    mx[r] = fmaxf(acc[mi][nj][r], other) + bias[mi][r];
                }
                if ((ln & 1) == 0) {
                    int kk = l >> 1;
                    if (which == 1) {
                        half4_t v = { (half_t)mx[0], (half_t)mx[1],
                                      (half_t)mx[2], (half_t)mx[3] };
                        *(half4_t*)(phiT + ((size_t)b * KLEN + kk) * CI + o) = v;
                    } else {
                        // permuted k index: v = t*32 + quad*8 + jh*4 + r
                        int loc = kk & 63;
                        int v = ((loc >> 5) & 1) * 32 + ((loc >> 2) & 3) * 8
                              + ((loc >> 4) & 1) * 4 + (loc & 3);
                        int kdst = (kk & ~63) | v;
                        #pragma unroll
                        for (int r = 0; r < 4; r++)
                            gperm[((size_t)b * CI + o + r) * KLEN + kdst] =
                                (half_t)mx[r];
                    }
                }
            }
        }
    }
}

// ---------------------------------------------------------------------------
// Kernel 2: MFMA flash attention. Fragment-order LDS (conflict-free b128);
// PV runs 16x16x32 (full rate): B-operand for P is a register pack of the
// S' C-layout thanks to gperm's k-permutation.
// Grid (B, L/64), 4 waves x 16q.
// ---------------------------------------------------------------------------
__global__ __launch_bounds__(256, 2) void attn_kernel(
    const half_t* __restrict__ thetaT,   // [B][L][CI]
    const half_t* __restrict__ phiT,     // [B][KLEN][CI]
    const half_t* __restrict__ gperm,    // [B][CI][KLEN] k-permuted
    half_t* __restrict__ yhT)            // [B][LEN][CI]
{
    __shared__ half_t phi_s[64 * 256];   // frag-order: granule (k16*8+ch)*64+lane
    __shared__ half_t g_s[256 * 64];     // frag-order: granule (tc*16+csub)*64+lane

    const int b    = blockIdx.x;
    const int q0   = blockIdx.y * 64;
    const int t    = threadIdx.x;
    const int w    = t >> 6;
    const int lane = t & 63;
    const int ln   = lane & 15;
    const int quad = lane >> 4;
    const int qw   = q0 + w * 16;

    half8_t thf[8];
    {
        const half_t* thb = thetaT + ((size_t)b * LEN + qw + ln) * CI + quad * 8;
        #pragma unroll
        for (int ch = 0; ch < 8; ch++)
            thf[ch] = *(const half8_t*)(thb + ch * 32);
    }

    floatx4 O[16];
    #pragma unroll
    for (int i = 0; i < 16; i++) O[i] = (floatx4)(0.0f);
    float m_run = -3.0e38f;
    float l_run = 0.0f;

    const half_t* phib = phiT + (size_t)b * KLEN * CI;
    const half_t* gpb  = gperm + (size_t)b * CI * KLEN;

    for (int kt = 0; kt < KLEN; kt += 64) {
        __syncthreads();
        // stage phi tile: 32 granule-groups (k16,ch), 8 per wave
        #pragma unroll
        for (int ii = 0; ii < 8; ii++) {
            int grp = w * 8 + ii;
            int k16 = grp >> 3, ch = grp & 7;
            async16(&phi_s[grp * 512],
                    phib + (size_t)(kt + k16 * 16 + ln) * CI + ch * 32 + quad * 8);
        }
        // stage g tile: 32 granule-groups (tc,csub), 8 per wave
        #pragma unroll
        for (int ii = 0; ii < 8; ii++) {
            int grp = w * 8 + ii;
            int tc = grp >> 4, csub = grp & 15;
            async16(&g_s[grp * 512],
                    gpb + (size_t)(csub * 16 + ln) * KLEN + kt + tc * 32 + quad * 8);
        }
        __syncthreads();

        // ---- S' = phi^T theta ----
        floatx4 S[4];
        #pragma unroll
        for (int k16 = 0; k16 < 4; k16++) S[k16] = (floatx4)(0.0f);
        #pragma unroll
        for (int k16 = 0; k16 < 4; k16++)
            #pragma unroll
            for (int ch = 0; ch < 8; ch++) {
                half8_t a = *(const half8_t*)&phi_s[(k16 * 8 + ch) * 512 + lane * 8];
                S[k16] = __builtin_amdgcn_mfma_f32_16x16x32_f16(
                             a, thf[ch], S[k16], 0, 0, 0);
            }

        // ---- online softmax ----
        float tmax = S[0][0];
        #pragma unroll
        for (int k16 = 0; k16 < 4; k16++)
            #pragma unroll
            for (int r = 0; r < 4; r++) tmax = fmaxf(tmax, S[k16][r]);
        tmax = fmaxf(tmax, __shfl_xor(tmax, 16));
        tmax = fmaxf(tmax, __shfl_xor(tmax, 32));
        float m_new = fmaxf(m_run, tmax);
        float alpha = __expf(m_run - m_new);
        m_run = m_new;
        l_run *= alpha;

        float p[4][4];
        #pragma unroll
        for (int k16 = 0; k16 < 4; k16++) {
            #pragma unroll
            for (int r = 0; r < 4; r++) {
                p[k16][r] = __expf(S[k16][r] - m_new);
                l_run += p[k16][r];
            }
        }
        // pack P into two K=32 B-frags: j=0..3 from k16=2tc, j=4..7 from 2tc+1
        half8_t Pf[2];
        #pragma unroll
        for (int tc = 0; tc < 2; tc++) {
            half8_t pv = { (half_t)p[2*tc][0],   (half_t)p[2*tc][1],
                           (half_t)p[2*tc][2],   (half_t)p[2*tc][3],
                           (half_t)p[2*tc+1][0], (half_t)p[2*tc+1][1],
                           (half_t)p[2*tc+1][2], (half_t)p[2*tc+1][3] };
            Pf[tc] = pv;
        }
        #pragma unroll
        for (int i = 0; i < 16; i++) O[i] *= alpha;

        // ---- PV: O[c][q] += g * P, K=32 full-rate ----
        #pragma unroll
        for (int tc = 0; tc < 2; tc++)
            #pragma unroll
            for (int csub = 0; csub < 16; csub++) {
                half8_t a = *(const half8_t*)&g_s[(tc * 16 + csub) * 512 + lane * 8];
                O[csub] = __builtin_amdgcn_mfma_f32_16x16x32_f16(
                              a, Pf[tc], O[csub], 0, 0, 0);
            }
    }

    l_run += __shfl_xor(l_run, 16);
    l_run += __shfl_xor(l_run, 32);
    float inv = 1.0f / l_run;
    half_t* yb = yhT + ((size_t)b * LEN + qw + ln) * CI;
    #pragma unroll
    for (int csub = 0; csub < 16; csub++) {
        int c = csub * 16 + quad * 4;
        half4_t v = { (half_t)(O[csub][0] * inv), (half_t)(O[csub][1] * inv),
                      (half_t)(O[csub][2] * inv), (half_t)(O[csub][3] * inv) };
        *(half4_t*)(yb + c) = v;
    }
}

// ---------------------------------------------------------------------------
// Kernel 3: MFMA zgemm, fragment-order LDS. z into d_out + BN partial sums.
// Grid (L/128, 4, B).
// ---------------------------------------------------------------------------
__global__ __launch_bounds__(256, 2) void zmm_kernel(
    const half_t* __restrict__ yhT, const half_t* __restrict__ wzh,
    const float* __restrict__ wzb, float* __restrict__ z,
    float* __restrict__ bns, float* __restrict__ bnq)
{
    __shared__ half_t ysm[128 * 32];
    __shared__ half_t wsm[128 * 32];

    const int b  = blockIdx.z;
    const int o0 = blockIdx.y * 128;
    const int l0 = blockIdx.x * 128;
    const int t  = threadIdx.x;
    const int lane = t & 63, w = t >> 6;
    const int ln = lane & 15, quad = lane >> 4;
    const int wm = w >> 1, wn = w & 1;

    floatx4 acc[4][4];
    #pragma unroll
    for (int mi = 0; mi < 4; mi++)
        #pragma unroll
        for (int nj = 0; nj < 4; nj++) acc[mi][nj] = (floatx4)(0.0f);

    const half_t* yb = yhT + ((size_t)b * LEN + l0) * CI;
    const half_t* Wb = wzh + (size_t)o0 * CI;

    for (int k0 = 0; k0 < 256; k0 += 32) {
        __syncthreads();
        #pragma unroll
        for (int it = 0; it < 2; it++) {
            int grp = w * 2 + it;
            async16(&ysm[grp * 512],
                    yb + (size_t)(grp * 16 + ln) * CI + k0 + quad * 8);
            async16(&wsm[grp * 512],
                    Wb + (size_t)(grp * 16 + ln) * CI + k0 + quad * 8);
        }
        __syncthreads();
        half8_t af[4], bf[4];
        #pragma unroll
        for (int mi = 0; mi < 4; mi++)
            af[mi] = *(const half8_t*)&ysm[(wm * 4 + mi) * 512 + lane * 8];
        #pragma unroll
        for (int nj = 0; nj < 4; nj++)
            bf[nj] = *(const half8_t*)&wsm[(wn * 4 + nj) * 512 + lane * 8];
        #pragma unroll
        for (int mi = 0; mi < 4; mi++)
            #pragma unroll
            for (int nj = 0; nj < 4; nj++)
                acc[mi][nj] = __builtin_amdgcn_mfma_f32_16x16x32_f16(
                                  af[mi], bf[nj], acc[mi][nj], 0, 0, 0);
    }

    // C: row = l = quad*4+r (m side = y), col = o = ln (n side = W)
    float s[4] = {0, 0, 0, 0}, s2[4] = {0, 0, 0, 0};
    #pragma unroll
    for (int nj = 0; nj < 4; nj++) {
        int o = o0 + wn * 64 + nj * 16 + ln;
        float bo = wzb[o];
        #pragma unroll
        for (int mi = 0; mi < 4; mi++) {
            int l = l0 + wm * 64 + mi * 16 + quad * 4;
            float4 v = make_float4(acc[mi][nj][0] + bo, acc[mi][nj][1] + bo,
                                   acc[mi][nj][2] + bo, acc[mi][nj][3] + bo);
            *(float4*)(z + ((size_t)b * CIN + o) * LEN + l) = v;
            s[nj]  += (v.x + v.y) + (v.z + v.w);
            s2[nj] += (v.x * v.x + v.y * v.y) + (v.z * v.z + v.w * v.w);
        }
    }
    #pragma unroll
    for (int nj = 0; nj < 4; nj++) {
        float sv = s[nj], qv = s2[nj];
        sv += __shfl_xor(sv, 16); sv += __shfl_xor(sv, 32);
        qv += __shfl_xor(qv, 16); qv += __shfl_xor(qv, 32);
        if (quad == 0) {
            int o = o0 + wn * 64 + nj * 16 + ln;
            atomicAdd(&bns[o], sv);
            atomicAdd(&bnq[o], qv);
        }
    }
}

// ---------------------------------------------------------------------------
// Kernel 4: BN normalize (batch stats, biased var) + residual, in-place.
// ---------------------------------------------------------------------------
__global__ __launch_bounds__(256) void bn_kernel(
    float* __restrict__ z, const float* __restrict__ x,
    const float* __restrict__ bns, const float* __restrict__ bnq,
    const float* __restrict__ gamma, const float* __restrict__ beta)
{
    size_t i4 = (size_t)blockIdx.x * 256 + threadIdx.x;
    size_t base = i4 << 2;
    int c = (int)((base >> 12) & (CIN - 1));
    const float invn = 1.0f / (BATCH * LEN);
    float mean = bns[c] * invn;
    float var  = bnq[c] * invn - mean * mean;
    float sc = gamma[c] * rsqrtf(var + 1e-5f);
    float sh = beta[c] - mean * sc;
    float4 zv = *(const float4*)(z + base);
    float4 xv = *(const float4*)(x + base);
    float4 o;
    o.x = zv.x * sc + sh + xv.x;
    o.y = zv.y * sc + sh + xv.y;
    o.z = zv.z * sc + sh + xv.z;
    o.w = zv.w * sc + sh + xv.w;
    *(float4*)(z + base) = o;
}

// ---------------------------------------------------------------------------
extern "C" void kernel_launch(void* const* d_in, const int* in_sizes, int n_in,
                              void* d_out, int out_size, void* d_ws, size_t ws_size,
                              hipStream_t stream)
{
    const float* x     = (const float*)d_in[0];
    const float* tw    = (const float*)d_in[1];
    const float* tb    = (const float*)d_in[2];
    const float* pw    = (const float*)d_in[3];
    const float* pb    = (const float*)d_in[4];
    const float* gw    = (const float*)d_in[5];
    const float* gb    = (const float*)d_in[6];
    const float* wzw   = (const float*)d_in[7];
    const float* wzb   = (const float*)d_in[8];
    const float* gamma = (const float*)d_in[9];
    const float* beta  = (const float*)d_in[10];

    float* out = (float*)d_out;

    half_t* xhT    = (half_t*)d_ws;                              // 33.6 MB
    half_t* thetaT = xhT    + (size_t)BATCH * LEN * CIN;         // 16.8 MB
    half_t* phiT   = thetaT + (size_t)BATCH * LEN * CI;          //  8.4 MB
    half_t* gperm  = phiT   + (size_t)BATCH * KLEN * CI;         //  8.4 MB
    half_t* yhT    = gperm  + (size_t)BATCH * CI * KLEN;         // 16.8 MB
    half_t* Wh     = yhT    + (size_t)BATCH * LEN * CI;          // 768 KB
    half_t* wzh    = Wh     + (size_t)768 * 512;                 // 256 KB
    float*  bns    = (float*)(wzh + (size_t)512 * 256);
    float*  bnq    = bns + CIN;

    hipMemsetAsync(bns, 0, 2 * CIN * sizeof(float), stream);

    wconv_kernel<<<256, 256, 0, stream>>>(tw, pw, gw, wzw, Wh, wzh);

    xpose_kernel<<<dim3(LEN / 64, CIN / 64, BATCH), 256, 0, stream>>>(x, xhT);

    projmm_kernel<<<dim3(LEN / 128, 6, BATCH), 256, 0, stream>>>(
        xhT, Wh, tb, pb, gb, thetaT, phiT, gperm);

    attn_kernel<<<dim3(BATCH, LEN / 64), 256, 0, stream>>>(
        thetaT, phiT, gperm, yhT);

    zmm_kernel<<<dim3(LEN / 128, CIN / 128, BATCH), 256, 0, stream>>>(
        yhT, wzh, wzb, out, bns, bnq);

    bn_kernel<<<(BATCH * CIN * LEN) / 4 / 256, 256, 0, stream>>>(
        out, x, bns, bnq, gamma, beta);
}

// Round 5
// 341.306 us; speedup vs baseline: 1.0770x; 1.0770x over previous
//
#include <hip/hip_runtime.h>

// Problem constants: B=8, C=512, L=4096, Ci=256, K=L/2=2048
#define BATCH 8
#define CIN   512
#define LEN   4096
#define CI    256
#define KLEN  2048

typedef _Float16 half_t;
typedef _Float16 half2_t __attribute__((ext_vector_type(2)));
typedef _Float16 half4_t __attribute__((ext_vector_type(4)));
typedef _Float16 half8_t __attribute__((ext_vector_type(8)));
typedef float    floatx4 __attribute__((ext_vector_type(4)));

// async global->LDS 16B: LDS side is wave-uniform base + lane*16.
__device__ __forceinline__ void async16(void* lds_dst, const void* g_src) {
    __builtin_amdgcn_global_load_lds(
        (const __attribute__((address_space(1))) unsigned int*)g_src,
        (__attribute__((address_space(3))) unsigned int*)lds_dst,
        16, 0, 0);
}

// ---------------------------------------------------------------------------
// Kernel A: convert+transpose x[b][c][l] f32 -> xhT[b][l][c] f16.
// ---------------------------------------------------------------------------
__global__ __launch_bounds__(256) void xpose_kernel(
    const float* __restrict__ x, half_t* __restrict__ xhT)
{
    __shared__ half_t tile[64][72];
    const int b = blockIdx.z, c0 = blockIdx.y * 64, l0 = blockIdx.x * 64;
    const int t = threadIdx.x;
    #pragma unroll
    for (int i = 0; i < 4; i++) {
        int fid = t + 256 * i;
        int c = fid >> 4, lb = (fid & 15) << 2;
        float4 v = *(const float4*)(x + ((size_t)b * CIN + c0 + c) * LEN + l0 + lb);
        tile[lb + 0][c] = (half_t)v.x;
        tile[lb + 1][c] = (half_t)v.y;
        tile[lb + 2][c] = (half_t)v.z;
        tile[lb + 3][c] = (half_t)v.w;
    }
    __syncthreads();
    #pragma unroll
    for (int i = 0; i < 2; i++) {
        int fid = t + 256 * i;
        int l = fid >> 3, cb = (fid & 7) << 3;
        half8_t v = *(const half8_t*)&tile[l][cb];
        *(half8_t*)(xhT + ((size_t)b * LEN + l0 + l) * CIN + c0 + cb) = v;
    }
}

// ---------------------------------------------------------------------------
// Kernel B: convert weights to fp16. Wh[768][512], wzh[512][256].
// ---------------------------------------------------------------------------
__global__ __launch_bounds__(256) void wconv_kernel(
    const float* __restrict__ tw, const float* __restrict__ pw,
    const float* __restrict__ gw, const float* __restrict__ wzw,
    half_t* __restrict__ Wh, half_t* __restrict__ wzh)
{
    size_t base = ((size_t)blockIdx.x * 256 + threadIdx.x) * 8;
    const float* src;
    half_t* dst;
    if (base < 768 * 512) {
        size_t o = base >> 9, c = base & 511;
        src = (o < 256 ? tw + o * 512
                       : (o < 512 ? pw + (o - 256) * 512 : gw + (o - 512) * 512)) + c;
        dst = Wh + base;
    } else {
        size_t off = base - 768 * 512;
        src = wzw + off;
        dst = wzh + off;
    }
    float4 a = *(const float4*)src, b2 = *(const float4*)(src + 4);
    half8_t h = { (half_t)a.x, (half_t)a.y, (half_t)a.z, (half_t)a.w,
                  (half_t)b2.x, (half_t)b2.y, (half_t)b2.z, (half_t)b2.w };
    *(half8_t*)dst = h;
}

// ---------------------------------------------------------------------------
// Kernel 1: MFMA projection GEMM (round-3 staging pattern: linear LDS,
// contiguous-row global gathers).  out[o,l] = sum_c Wh[o,c] xhT[l,c];
// o=0..767 = theta/phi/g; maxpool fused.  g is written in "granule-stream"
// layout: per batch, per 64-k tile, 32 granules of 1KB, each granule the
// exact PV A-fragment (lane*16B) so attn can global-load it coalesced.
// Grid (L/128, 6, B).
// ---------------------------------------------------------------------------
__global__ __launch_bounds__(256, 2) void projmm_kernel(
    const half_t* __restrict__ xhT, const half_t* __restrict__ Wh,
    const float* __restrict__ tb, const float* __restrict__ pb,
    const float* __restrict__ gb,
    half_t* __restrict__ thetaT, half_t* __restrict__ phiT,
    half_t* __restrict__ gperm)
{
    __shared__ half_t wsm[128 * 32];   // [o][c] 64B rows
    __shared__ half_t xsm[128 * 32];   // [l][c] 64B rows

    const int b  = blockIdx.z;
    const int o0 = blockIdx.y * 128;
    const int l0 = blockIdx.x * 128;
    const int t  = threadIdx.x;
    const int lane = t & 63, w = t >> 6;
    const int ln = lane & 15, quad = lane >> 4;
    const int wm = w >> 1, wn = w & 1;

    floatx4 acc[4][4];
    #pragma unroll
    for (int mi = 0; mi < 4; mi++)
        #pragma unroll
        for (int nj = 0; nj < 4; nj++) acc[mi][nj] = (floatx4)(0.0f);

    const half_t* Wb = Wh + (size_t)o0 * 512;
    const half_t* xb = xhT + ((size_t)b * LEN + l0) * CIN;

    for (int k0 = 0; k0 < 512; k0 += 32) {
        __syncthreads();
        #pragma unroll
        for (int it = 0; it < 2; it++) {
            int off = t * 16 + it * 4096;       // LDS byte offset
            int row = off >> 6, c8 = (off >> 4) & 3;
            async16(&wsm[off >> 1], Wb + (size_t)row * 512 + k0 + c8 * 8);
            async16(&xsm[off >> 1], xb + (size_t)row * CIN + k0 + c8 * 8);
        }
        __syncthreads();
        half8_t af[4], bf[4];
        #pragma unroll
        for (int mi = 0; mi < 4; mi++)
            af[mi] = *(const half8_t*)&wsm[(wm * 64 + mi * 16 + ln) * 32 + quad * 8];
        #pragma unroll
        for (int nj = 0; nj < 4; nj++)
            bf[nj] = *(const half8_t*)&xsm[(wn * 64 + nj * 16 + ln) * 32 + quad * 8];
        #pragma unroll
        for (int mi = 0; mi < 4; mi++)
            #pragma unroll
            for (int nj = 0; nj < 4; nj++)
                acc[mi][nj] = __builtin_amdgcn_mfma_f32_16x16x32_f16(
                                  af[mi], bf[nj], acc[mi][nj], 0, 0, 0);
    }

    const int which = o0 >> 8;          // 0=theta, 1=phi, 2=g
    const int obase = o0 & 255;
    const float* Bp = which == 0 ? tb : (which == 1 ? pb : gb);

    float bias[4][4];
    #pragma unroll
    for (int mi = 0; mi < 4; mi++)
        #pragma unroll
        for (int r = 0; r < 4; r++)
            bias[mi][r] = Bp[obase + wm * 64 + mi * 16 + quad * 4 + r];

    if (which == 0) {
        #pragma unroll
        for (int mi = 0; mi < 4; mi++) {
            int o = obase + wm * 64 + mi * 16 + quad * 4;
            #pragma unroll
            for (int nj = 0; nj < 4; nj++) {
                int l = l0 + wn * 64 + nj * 16 + ln;
                half4_t v = { (half_t)(acc[mi][nj][0] + bias[mi][0]),
                              (half_t)(acc[mi][nj][1] + bias[mi][1]),
                              (half_t)(acc[mi][nj][2] + bias[mi][2]),
                              (half_t)(acc[mi][nj][3] + bias[mi][3]) };
                *(half4_t*)(thetaT + ((size_t)b * LEN + l) * CI + o) = v;
            }
        }
    } else {
        #pragma unroll
        for (int mi = 0; mi < 4; mi++) {
            int ob4 = obase + wm * 64 + mi * 16 + quad * 4;
            #pragma unroll
            for (int nj = 0; nj < 4; nj++) {
                int l = l0 + wn * 64 + nj * 16 + ln;
                float mx[4];
                #pragma unroll
                for (int r = 0; r < 4; r++) {
                    float other = __shfl_xor(acc[mi][nj][r], 1);
                    mx[r] = fmaxf(acc[mi][nj][r], other) + bias[mi][r];
                }
                if ((ln & 1) == 0) {
                    int kk = l >> 1;
                    if (which == 1) {
                        half4_t v = { (half_t)mx[0], (half_t)mx[1],
                                      (half_t)mx[2], (half_t)mx[3] };
                        *(half4_t*)(phiT + ((size_t)b * KLEN + kk) * CI + ob4) = v;
                    } else {
                        // granule-stream address for g
                        int ktile = kk >> 6, kl = kk & 63;
                        int tc  = kl >> 5;
                        int h16 = (kl >> 4) & 1;
                        int qd  = (kl & 15) >> 2;
                        int j   = h16 * 4 + (kl & 3);
                        size_t base = (size_t)b * (CI * KLEN)
                                    + (size_t)ktile * 16384 + tc * 8192 + j;
                        #pragma unroll
                        for (int r = 0; r < 4; r++) {
                            int c = ob4 + r;
                            int csub = c >> 4, lnc = c & 15;
                            gperm[base + csub * 512 + (qd * 16 + lnc) * 8] =
                                (half_t)mx[r];
                        }
                    }
                }
            }
        }
    }
}

// ---------------------------------------------------------------------------
// Kernel 2: MFMA flash attention.
//  - phi staged to LDS with contiguous-row gather + rotate swizzle
//    (slot = (granule + 4*row) & 31): S' reads are 2-way (free).
//  - g read DIRECTLY global->VGPR from granule-stream gperm (1KB coalesced
//    per wave-load, L1-shared across the block's 4 waves). No g LDS.
//  - PV at K=32 with register-packed P.
// Grid (B, L/64), 4 waves x 16q.
// ---------------------------------------------------------------------------
__global__ __launch_bounds__(256, 2) void attn_kernel(
    const half_t* __restrict__ thetaT,   // [B][L][CI]
    const half_t* __restrict__ phiT,     // [B][KLEN][CI]
    const half_t* __restrict__ gperm,    // [B] granule-stream
    half_t* __restrict__ yhT)            // [B][LEN][CI]
{
    __shared__ half_t phi_s[64 * 256];   // 64 rows x 512B, rotate-swizzled

    const int b    = blockIdx.x;
    const int q0   = blockIdx.y * 64;
    const int t    = threadIdx.x;
    const int w    = t >> 6;
    const int lane = t & 63;
    const int ln   = lane & 15;
    const int quad = lane >> 4;
    const int qw   = q0 + w * 16;

    half8_t thf[8];
    {
        const half_t* thb = thetaT + ((size_t)b * LEN + qw + ln) * CI + quad * 8;
        #pragma unroll
        for (int ch = 0; ch < 8; ch++)
            thf[ch] = *(const half8_t*)(thb + ch * 32);
    }

    floatx4 O[16];
    #pragma unroll
    for (int i = 0; i < 16; i++) O[i] = (floatx4)(0.0f);
    float m_run = -3.0e38f;
    float l_run = 0.0f;

    const half_t* phib = phiT + (size_t)b * KLEN * CI;
    const half_t* gpb  = gperm + (size_t)b * (CI * KLEN);

    for (int kt = 0; kt < 32; kt++) {
        __syncthreads();   // previous iteration's phi_s reads complete
        // ---- stage phi tile (32KB): linear LDS, rotated rows ----
        #pragma unroll
        for (int it = 0; it < 8; it++) {
            int o = t * 16 + it * 4096;
            int row = o >> 9, slot = (o >> 4) & 31;
            int gsrc = (slot - 4 * row) & 31;
            async16(&phi_s[o >> 1],
                    phib + (size_t)(kt * 64 + row) * CI + gsrc * 8);
        }
        const half_t* gkt = gpb + (size_t)kt * 16384;
        // prefetch g granules 0..7 (tc=0, csub 0..7) — independent of LDS
        half8_t gfa[8], gfb[8];
        #pragma unroll
        for (int cs = 0; cs < 8; cs++)
            gfa[cs] = *(const half8_t*)(gkt + cs * 512 + lane * 8);
        __syncthreads();   // phi_s visible

        // ---- S' = phi^T theta ----
        floatx4 S[4];
        #pragma unroll
        for (int k16 = 0; k16 < 4; k16++) S[k16] = (floatx4)(0.0f);
        #pragma unroll
        for (int k16 = 0; k16 < 4; k16++) {
            int row = k16 * 16 + ln;
            #pragma unroll
            for (int ch = 0; ch < 8; ch++) {
                int slot = (ch * 4 + quad + 4 * ln) & 31;
                half8_t a = *(const half8_t*)&phi_s[row * 256 + slot * 8];
                S[k16] = __builtin_amdgcn_mfma_f32_16x16x32_f16(
                             a, thf[ch], S[k16], 0, 0, 0);
            }
        }

        // ---- online softmax (per-lane state for q = lane&15) ----
        float tmax = S[0][0];
        #pragma unroll
        for (int k16 = 0; k16 < 4; k16++)
            #pragma unroll
            for (int r = 0; r < 4; r++) tmax = fmaxf(tmax, S[k16][r]);
        tmax = fmaxf(tmax, __shfl_xor(tmax, 16));
        tmax = fmaxf(tmax, __shfl_xor(tmax, 32));
        float m_new = fmaxf(m_run, tmax);
        float alpha = __expf(m_run - m_new);
        m_run = m_new;
        l_run *= alpha;

        float p[4][4];
        #pragma unroll
        for (int k16 = 0; k16 < 4; k16++)
            #pragma unroll
            for (int r = 0; r < 4; r++) {
                p[k16][r] = __expf(S[k16][r] - m_new);
                l_run += p[k16][r];
            }
        half8_t Pf[2];
        #pragma unroll
        for (int tc = 0; tc < 2; tc++) {
            half8_t pv = { (half_t)p[2*tc][0],   (half_t)p[2*tc][1],
                           (half_t)p[2*tc][2],   (half_t)p[2*tc][3],
                           (half_t)p[2*tc+1][0], (half_t)p[2*tc+1][1],
                           (half_t)p[2*tc+1][2], (half_t)p[2*tc+1][3] };
            Pf[tc] = pv;
        }
        #pragma unroll
        for (int i = 0; i < 16; i++) O[i] *= alpha;

        // ---- PV: K=32, g frags from global, software-pipelined ----
        #pragma unroll
        for (int cs = 0; cs < 8; cs++)           // granules 8..15 (tc0 hi)
            gfb[cs] = *(const half8_t*)(gkt + (8 + cs) * 512 + lane * 8);
        #pragma unroll
        for (int cs = 0; cs < 8; cs++)
            O[cs] = __builtin_amdgcn_mfma_f32_16x16x32_f16(
                        gfa[cs], Pf[0], O[cs], 0, 0, 0);
        #pragma unroll
        for (int cs = 0; cs < 8; cs++)           // granules 16..23 (tc1 lo)
            gfa[cs] = *(const half8_t*)(gkt + (16 + cs) * 512 + lane * 8);
        #pragma unroll
        for (int cs = 0; cs < 8; cs++)
            O[8 + cs] = __builtin_amdgcn_mfma_f32_16x16x32_f16(
                            gfb[cs], Pf[0], O[8 + cs], 0, 0, 0);
        #pragma unroll
        for (int cs = 0; cs < 8; cs++)           // granules 24..31 (tc1 hi)
            gfb[cs] = *(const half8_t*)(gkt + (24 + cs) * 512 + lane * 8);
        #pragma unroll
        for (int cs = 0; cs < 8; cs++)
            O[cs] = __builtin_amdgcn_mfma_f32_16x16x32_f16(
                        gfa[cs], Pf[1], O[cs], 0, 0, 0);
        #pragma unroll
        for (int cs = 0; cs < 8; cs++)
            O[8 + cs] = __builtin_amdgcn_mfma_f32_16x16x32_f16(
                            gfb[cs], Pf[1], O[8 + cs], 0, 0, 0);
    }

    l_run += __shfl_xor(l_run, 16);
    l_run += __shfl_xor(l_run, 32);
    float inv = 1.0f / l_run;
    half_t* yb = yhT + ((size_t)b * LEN + qw + ln) * CI;
    #pragma unroll
    for (int csub = 0; csub < 16; csub++) {
        int c = csub * 16 + quad * 4;
        half4_t v = { (half_t)(O[csub][0] * inv), (half_t)(O[csub][1] * inv),
                      (half_t)(O[csub][2] * inv), (half_t)(O[csub][3] * inv) };
        *(half4_t*)(yb + c) = v;
    }
}

// ---------------------------------------------------------------------------
// Kernel 3: MFMA zgemm (round-3 staging). z into d_out + BN partial sums.
// Grid (L/128, 4, B).
// ---------------------------------------------------------------------------
__global__ __launch_bounds__(256, 2) void zmm_kernel(
    const half_t* __restrict__ yhT, const half_t* __restrict__ wzh,
    const float* __restrict__ wzb, float* __restrict__ z,
    float* __restrict__ bns, float* __restrict__ bnq)
{
    __shared__ half_t ysm[128 * 32];
    __shared__ half_t wsm[128 * 32];

    const int b  = blockIdx.z;
    const int o0 = blockIdx.y * 128;
    const int l0 = blockIdx.x * 128;
    const int t  = threadIdx.x;
    const int lane = t & 63, w = t >> 6;
    const int ln = lane & 15, quad = lane >> 4;
    const int wm = w >> 1, wn = w & 1;

    floatx4 acc[4][4];
    #pragma unroll
    for (int mi = 0; mi < 4; mi++)
        #pragma unroll
        for (int nj = 0; nj < 4; nj++) acc[mi][nj] = (floatx4)(0.0f);

    const half_t* yb = yhT + ((size_t)b * LEN + l0) * CI;
    const half_t* Wb = wzh + (size_t)o0 * CI;

    for (int k0 = 0; k0 < 256; k0 += 32) {
        __syncthreads();
        #pragma unroll
        for (int it = 0; it < 2; it++) {
            int off = t * 16 + it * 4096;
            int row = off >> 6, c8 = (off >> 4) & 3;
            async16(&ysm[off >> 1], yb + (size_t)row * CI + k0 + c8 * 8);
            async16(&wsm[off >> 1], Wb + (size_t)row * CI + k0 + c8 * 8);
        }
        __syncthreads();
        half8_t af[4], bf[4];
        #pragma unroll
        for (int mi = 0; mi < 4; mi++)
            af[mi] = *(const half8_t*)&ysm[(wm * 64 + mi * 16 + ln) * 32 + quad * 8];
        #pragma unroll
        for (int nj = 0; nj < 4; nj++)
            bf[nj] = *(const half8_t*)&wsm[(wn * 64 + nj * 16 + ln) * 32 + quad * 8];
        #pragma unroll
        for (int mi = 0; mi < 4; mi++)
            #pragma unroll
            for (int nj = 0; nj < 4; nj++)
                acc[mi][nj] = __builtin_amdgcn_mfma_f32_16x16x32_f16(
                                  af[mi], bf[nj], acc[mi][nj], 0, 0, 0);
    }

    float s[4] = {0, 0, 0, 0}, s2[4] = {0, 0, 0, 0};
    #pragma unroll
    for (int nj = 0; nj < 4; nj++) {
        int o = o0 + wn * 64 + nj * 16 + ln;
        float bo = wzb[o];
        #pragma unroll
        for (int mi = 0; mi < 4; mi++) {
            int l = l0 + wm * 64 + mi * 16 + quad * 4;
            float4 v = make_float4(acc[mi][nj][0] + bo, acc[mi][nj][1] + bo,
                                   acc[mi][nj][2] + bo, acc[mi][nj][3] + bo);
            *(float4*)(z + ((size_t)b * CIN + o) * LEN + l) = v;
            s[nj]  += (v.x + v.y) + (v.z + v.w);
            s2[nj] += (v.x * v.x + v.y * v.y) + (v.z * v.z + v.w * v.w);
        }
    }
    #pragma unroll
    for (int nj = 0; nj < 4; nj++) {
        float sv = s[nj], qv = s2[nj];
        sv += __shfl_xor(sv, 16); sv += __shfl_xor(sv, 32);
        qv += __shfl_xor(qv, 16); qv += __shfl_xor(qv, 32);
        if (quad == 0) {
            int o = o0 + wn * 64 + nj * 16 + ln;
            atomicAdd(&bns[o], sv);
            atomicAdd(&bnq[o], qv);
        }
    }
}

// ---------------------------------------------------------------------------
// Kernel 4: BN normalize (batch stats, biased var) + residual, in-place.
// ---------------------------------------------------------------------------
__global__ __launch_bounds__(256) void bn_kernel(
    float* __restrict__ z, const float* __restrict__ x,
    const float* __restrict__ bns, const float* __restrict__ bnq,
    const float* __restrict__ gamma, const float* __restrict__ beta)
{
    size_t i4 = (size_t)blockIdx.x * 256 + threadIdx.x;
    size_t base = i4 << 2;
    int c = (int)((base >> 12) & (CIN - 1));
    const float invn = 1.0f / (BATCH * LEN);
    float mean = bns[c] * invn;
    float var  = bnq[c] * invn - mean * mean;
    float sc = gamma[c] * rsqrtf(var + 1e-5f);
    float sh = beta[c] - mean * sc;
    float4 zv = *(const float4*)(z + base);
    float4 xv = *(const float4*)(x + base);
    float4 o;
    o.x = zv.x * sc + sh + xv.x;
    o.y = zv.y * sc + sh + xv.y;
    o.z = zv.z * sc + sh + xv.z;
    o.w = zv.w * sc + sh + xv.w;
    *(float4*)(z + base) = o;
}

// ---------------------------------------------------------------------------
extern "C" void kernel_launch(void* const* d_in, const int* in_sizes, int n_in,
                              void* d_out, int out_size, void* d_ws, size_t ws_size,
                              hipStream_t stream)
{
    const float* x     = (const float*)d_in[0];
    const float* tw    = (const float*)d_in[1];
    const float* tb    = (const float*)d_in[2];
    const float* pw    = (const float*)d_in[3];
    const float* pb    = (const float*)d_in[4];
    const float* gw    = (const float*)d_in[5];
    const float* gb    = (const float*)d_in[6];
    const float* wzw   = (const float*)d_in[7];
    const float* wzb   = (const float*)d_in[8];
    const float* gamma = (const float*)d_in[9];
    const float* beta  = (const float*)d_in[10];

    float* out = (float*)d_out;

    half_t* xhT    = (half_t*)d_ws;                              // 33.6 MB
    half_t* thetaT = xhT    + (size_t)BATCH * LEN * CIN;         // 16.8 MB
    half_t* phiT   = thetaT + (size_t)BATCH * LEN * CI;          //  8.4 MB
    half_t* gperm  = phiT   + (size_t)BATCH * KLEN * CI;         //  8.4 MB
    half_t* yhT    = gperm  + (size_t)BATCH * CI * KLEN;         // 16.8 MB
    half_t* Wh     = yhT    + (size_t)BATCH * LEN * CI;          // 768 KB
    half_t* wzh    = Wh     + (size_t)768 * 512;                 // 256 KB
    float*  bns    = (float*)(wzh + (size_t)512 * 256);
    float*  bnq    = bns + CIN;

    hipMemsetAsync(bns, 0, 2 * CIN * sizeof(float), stream);

    wconv_kernel<<<256, 256, 0, stream>>>(tw, pw, gw, wzw, Wh, wzh);

    xpose_kernel<<<dim3(LEN / 64, CIN / 64, BATCH), 256, 0, stream>>>(x, xhT);

    projmm_kernel<<<dim3(LEN / 128, 6, BATCH), 256, 0, stream>>>(
        xhT, Wh, tb, pb, gb, thetaT, phiT, gperm);

    attn_kernel<<<dim3(BATCH, LEN / 64), 256, 0, stream>>>(
        thetaT, phiT, gperm, yhT);

    zmm_kernel<<<dim3(LEN / 128, CIN / 128, BATCH), 256, 0, stream>>>(
        yhT, wzh, wzb, out, bns, bnq);

    bn_kernel<<<(BATCH * CIN * LEN) / 4 / 256, 256, 0, stream>>>(
        out, x, bns, bnq, gamma, beta);
}